// Round 8
// baseline (215.714 us; speedup 1.0000x reference)
//
#include <hip/hip_runtime.h>
#include <hip/hip_bf16.h>

// DotProductNonLocalBlock: B=8, C=512, N=3136 (pad 3200), E=256.
// No softmax => fully associative. Factored with DATA-INDEPENDENT
// P = wo·wv, Qt = wq^T·wk, u = wo·bv, r = bk^T·wq, w = Wk^T·bq, κ = bk·bq:
//   G  = X·X^T   [bf16 MFMA, split-K=2 col-interleaved partials, SYMMETRIC]
//   T  = Pd·Gp2 (K=1024 folds the reduce)
//   A2 = [T·Q + u·(Qt s)^T + (P s)·r^T]/N + u·r^T + I   (residual folded)
//   a2 = [T·w + u·(s·w) + (P s)·κ]/N + u·κ + bo
//   Out = (A2+I)·X + a2
// LEDGER: final-GEMM: 64x128 single-buf 2-barrier + xnp transpose-scatter B = best
//   (43us, R7). T4 counted-vmcnt on 2-phase loops: neutral. R5 identity-fold: +16us win.
// R7 lesson: prep_trans pinned ~45-48us across 3 builds (bytes 104->59MB, MLP 2x,
//   LDS removed) with occ stuck 20-25% at VGPR32/LDS8.7K => block-churn limited
//   (3200 sub-us blocks outrun the dispatch engine; waves never accumulate).
// R8: streaming path -> 800 persistent blocks x 4 tiles, 2-deep register
//   prefetch pipeline (static buffers, hand-unrolled). Weight path rides the
//   same 1-D grid at bid>=800. G11: cap grid, grid-stride, long-lived waves.

typedef __attribute__((ext_vector_type(8))) __bf16 bf16x8;
typedef __attribute__((ext_vector_type(8))) short s16x8;
typedef __attribute__((ext_vector_type(4))) float floatx4;

struct __align__(8) bh4 { __hip_bfloat16 x, y, z, w; };
struct __align__(16) bh8 { __hip_bfloat16 h[8]; };

__device__ __forceinline__ void load_lds16(const void* g, void* l) {
    __builtin_amdgcn_global_load_lds((const __attribute__((address_space(1))) void*)g,
                                     (__attribute__((address_space(3))) void*)l, 16, 0, 0);
}

// tile id -> (batch, c-block, n-block) for the streaming path (8*8*50 = 3200)
__device__ __forceinline__ void tile_coords(int tile, int& b, int& c0, int& n0) {
    b = tile / 400;
    int rem = tile - b * 400;
    c0 = (rem / 50) << 6;
    n0 = (rem % 50) << 6;
}

__device__ __forceinline__ void load_tile(const float* __restrict__ x, int tile,
                                          int nch, int cr, float4 (&vv)[2][2]) {
    int b, c0, n0; tile_coords(tile, b, c0, n0);
    const float* xb = x + (long long)b * 512 * 3136;
    int nn = n0 + nch * 8;
    if (nn >= 3136) nn = 3128;                  // clamp (pad tiles zeroed at store)
#pragma unroll
    for (int p = 0; p < 2; ++p) {
        const float* xr = xb + (long long)(c0 + cr + 32 * p) * 3136 + nn;
        vv[p][0] = *(const float4*)xr;
        vv[p][1] = *(const float4*)(xr + 4);
    }
}

__device__ __forceinline__ void proc_tile(__hip_bfloat16* __restrict__ xnp,
                                          float* __restrict__ s, int tile,
                                          int nch, int cr, float4 (&vv)[2][2]) {
    int b, c0, n0; tile_coords(tile, b, c0, n0);
    __hip_bfloat16* xno = xnp + (long long)b * 512 * 3200;
    const bool pad = (n0 >= 3136);
    float rsum[2];
#pragma unroll
    for (int p = 0; p < 2; ++p) {
        float4 v0 = vv[p][0], v1 = vv[p][1];
        if (pad) {
            v0 = make_float4(0.f, 0.f, 0.f, 0.f);
            v1 = make_float4(0.f, 0.f, 0.f, 0.f);
        }
        bh8 o;
        o.h[0] = __float2bfloat16(v0.x); o.h[1] = __float2bfloat16(v0.y);
        o.h[2] = __float2bfloat16(v0.z); o.h[3] = __float2bfloat16(v0.w);
        o.h[4] = __float2bfloat16(v1.x); o.h[5] = __float2bfloat16(v1.y);
        o.h[6] = __float2bfloat16(v1.z); o.h[7] = __float2bfloat16(v1.w);
        *(bh8*)&xno[(long long)(c0 + cr + 32 * p) * 3200 + n0 + nch * 8] = o;
        float rs = v0.x + v0.y + v0.z + v0.w + v1.x + v1.y + v1.z + v1.w;
        rs += __shfl_xor(rs, 1, 8);
        rs += __shfl_xor(rs, 2, 8);
        rs += __shfl_xor(rs, 4, 8);
        rsum[p] = rs;
    }
    if (!pad && nch == 0) {
        atomicAdd(&s[b * 512 + c0 + cr], rsum[0]);
        atomicAdd(&s[b * 512 + c0 + cr + 32], rsum[1]);
    }
}

// ---- fused: x->xnp streaming convert (persistent) + data-independent precompute ----
// bid <  800: streaming path, tiles {bid, bid+800, bid+1600, bid+2400},
//             2-deep register prefetch pipeline.
// bid >= 800: blk = bid-800:
//   blk in [0,64)   -> Pd tile (P = wo·wv, duplicated [P|P])
//   blk in [64,128) -> Qt tile (wq^T·wk)
//   blk 128,129     -> u/r/w vectors (256 channels each)
__global__ __launch_bounds__(256)
void prep_trans(const float* __restrict__ x, __hip_bfloat16* __restrict__ xnp,
                float* __restrict__ s,
                const float* __restrict__ wo, const float* __restrict__ wv,
                const float* __restrict__ wq, const float* __restrict__ wk,
                const float* __restrict__ bq, const float* __restrict__ bk,
                const float* __restrict__ bv,
                __hip_bfloat16* __restrict__ Pdb, __hip_bfloat16* __restrict__ Qtb,
                float* __restrict__ u, float* __restrict__ r, float* __restrict__ w,
                float* __restrict__ kap)
{
    __shared__ __align__(16) float smem[2 * 16 * 68];   // 8.7KB, weight path only
    const int tid = threadIdx.x;
    const int bid = blockIdx.x;

    if (bid >= 800) {
        // ---------- weight path ----------
        const int blk = bid - 800;
        if (blk >= 130) return;
        if (blk >= 128) {
            int c = (blk - 128) * 256 + tid;
            float su = 0.f, sr = 0.f, sw = 0.f;
            for (int e = 0; e < 256; ++e) {
                su = fmaf(wo[(long long)c * 256 + e], bv[e], su);
                sr = fmaf(bk[e], wq[(long long)e * 512 + c], sr);
                sw = fmaf(wk[(long long)e * 512 + c], bq[e], sw);
            }
            u[c] = su; r[c] = sr; w[c] = sw;
            if (c == 0) {
                float k2 = 0.f;
                for (int e = 0; e < 256; ++e) k2 = fmaf(bk[e], bq[e], k2);
                *kap = k2;
            }
            return;
        }
        const bool doQ = (blk >= 64);
        const int tt = blk & 63;
        const int m0 = (tt >> 3) * 64, n0 = (tt & 7) * 64;
        float (*As)[68] = (float(*)[68])smem;
        float (*Bs)[68] = (float(*)[68])(smem + 16 * 68);
        const int tx = tid & 15, ty = tid >> 4;
        const int lk = tid >> 4, lc = (tid & 15) * 4;
        const int lr = tid >> 2, lk4 = (tid & 3) * 4;
        float acc[4][4] = {};
        for (int k0 = 0; k0 < 256; k0 += 16) {
            float4 av, bv4;
            if (doQ) {
                av = *(const float4*)&wq[(long long)(k0 + lk) * 512 + m0 + lc];
                bv4 = *(const float4*)&wk[(long long)(k0 + lk) * 512 + n0 + lc];
            } else {
                av = *(const float4*)&wo[(long long)(m0 + lr) * 256 + k0 + lk4];
                bv4 = *(const float4*)&wv[(long long)(k0 + lk) * 512 + n0 + lc];
            }
            __syncthreads();
            if (doQ) {
                *(float4*)&As[lk][lc] = av;
            } else {
                As[lk4 + 0][lr] = av.x; As[lk4 + 1][lr] = av.y;
                As[lk4 + 2][lr] = av.z; As[lk4 + 3][lr] = av.w;
            }
            *(float4*)&Bs[lk][lc] = bv4;
            __syncthreads();
#pragma unroll
            for (int kk = 0; kk < 16; ++kk) {
                float a[4], b[4];
#pragma unroll
                for (int i = 0; i < 4; ++i) { a[i] = As[kk][ty * 4 + i]; b[i] = Bs[kk][tx * 4 + i]; }
#pragma unroll
                for (int i = 0; i < 4; ++i)
#pragma unroll
                    for (int j = 0; j < 4; ++j) acc[i][j] = fmaf(a[i], b[j], acc[i][j]);
            }
        }
        const int mo = m0 + ty * 4, no = n0 + tx * 4;
        if (doQ) {
#pragma unroll
            for (int i = 0; i < 4; ++i)
#pragma unroll
                for (int j = 0; j < 4; ++j)
                    Qtb[(long long)(mo + i) * 512 + no + j] = __float2bfloat16(acc[i][j]);
        } else {
#pragma unroll
            for (int i = 0; i < 4; ++i)
#pragma unroll
                for (int j = 0; j < 4; ++j) {
                    __hip_bfloat16 v = __float2bfloat16(acc[i][j]);
                    Pdb[(long long)(mo + i) * 1024 + no + j] = v;
                    Pdb[(long long)(mo + i) * 1024 + no + j + 512] = v;
                }
        }
        return;
    }

    // ---------- streaming path: 4 tiles, 2-deep register prefetch ----------
    const int nch = tid & 7;      // 8-float chunk within 64-n tile
    const int cr  = tid >> 3;     // 0..31
    float4 va[2][2], vb[2][2];    // static double-buffer (no runtime indexing)

    load_tile(x, bid,        nch, cr, va);
    load_tile(x, bid + 800,  nch, cr, vb);
    proc_tile(xnp, s, bid,        nch, cr, va);
    load_tile(x, bid + 1600, nch, cr, va);
    proc_tile(xnp, s, bid + 800,  nch, cr, vb);
    load_tile(x, bid + 2400, nch, cr, vb);
    proc_tile(xnp, s, bid + 1600, nch, cr, va);
    proc_tile(xnp, s, bid + 2400, nch, cr, vb);
}

// Wave-per-output: ps = P·s, sq = Qt·s, a2 = [T·w + u(s·w) + ps·κ]/N + uκ + bo.
__global__ __launch_bounds__(256)
void vec2_kernel(const __hip_bfloat16* __restrict__ T, const __hip_bfloat16* __restrict__ Pdb,
                 const __hip_bfloat16* __restrict__ Qtb, const float* __restrict__ s,
                 const float* __restrict__ u, const float* __restrict__ w,
                 const float* __restrict__ kap, const float* __restrict__ bo,
                 float* __restrict__ ps, float* __restrict__ sq, float* __restrict__ a2)
{
    const int idx = blockIdx.x * 4 + (threadIdx.x >> 6);   // b*512+c
    const int lane = threadIdx.x & 63;
    const int b = idx >> 9, c = idx & 511;
    const int j0 = lane * 8;
    const float* sb = s + b * 512;
    float4 s0 = *(const float4*)&sb[j0], s1 = *(const float4*)&sb[j0 + 4];
    float4 w0 = *(const float4*)&w[j0],  w1 = *(const float4*)&w[j0 + 4];
    bf16x8 pv = *(const bf16x8*)&Pdb[(long long)c * 1024 + j0];
    bf16x8 qv = *(const bf16x8*)&Qtb[(long long)c * 512 + j0];
    bf16x8 tv = *(const bf16x8*)&T[(long long)b * 262144 + (long long)c * 512 + j0];
    float sj[8] = {s0.x, s0.y, s0.z, s0.w, s1.x, s1.y, s1.z, s1.w};
    float wj[8] = {w0.x, w0.y, w0.z, w0.w, w1.x, w1.y, w1.z, w1.w};
    float aps = 0.f, asq = 0.f, atw = 0.f, asw = 0.f;
#pragma unroll
    for (int t = 0; t < 8; ++t) {
        aps = fmaf((float)pv[t], sj[t], aps);
        asq = fmaf((float)qv[t], sj[t], asq);
        atw = fmaf((float)tv[t], wj[t], atw);
        asw = fmaf(sj[t], wj[t], asw);
    }
#pragma unroll
    for (int m = 1; m < 64; m <<= 1) {
        aps += __shfl_xor(aps, m);
        asq += __shfl_xor(asq, m);
        atw += __shfl_xor(atw, m);
        asw += __shfl_xor(asw, m);
    }
    if (lane == 0) {
        ps[idx] = aps; sq[idx] = asq;
        float kp = *kap;
        a2[idx] = (atw + u[c] * asw + aps * kp) * (1.f / 3136.f) + u[c] * kp + bo[c];
    }
}

#define SWZ64(row) ((row) & 7)

// G GEMM with symmetric mirroring. 64x64 tile, BK=64, operands = xnp (both).
// Grid: x = batch + 8*ks (XCD affinity), y = triangular pair index (36).
// Counted-vmcnt double-buffered K-loop.
__global__ __launch_bounds__(256)
void mfma_g(const __hip_bfloat16* __restrict__ A, long long sA, int lda,
            __hip_bfloat16* __restrict__ C, long long sC, int ldc,
            int kLen)
{
    constexpr int BKT = 64;
    constexpr int CPR = BKT / 8;
    constexpr int NC = 64 * CPR / 256;
    constexpr int LSZ = 64 * BKT;
    __shared__ __hip_bfloat16 As[2 * LSZ];
    __shared__ __hip_bfloat16 Bs[2 * LSZ];
    const int tid = threadIdx.x;
    const int lane = tid & 63;
    const int w = tid >> 6;
    const int wm = (w >> 1) << 5;
    const int wn = (w & 1) << 5;
    const int ln = lane & 15;
    const int hi = lane >> 4;
    const int bx = blockIdx.x;
    const int batch = bx & 7, ks = bx >> 3;
    int p = blockIdx.y, mt = 0;
    while (p >= 8 - mt) { p -= 8 - mt; ++mt; }
    const int nt = mt + p;
    const int m0 = mt << 6, n0 = nt << 6;
    const long long k0 = (long long)ks * kLen;

    const __hip_bfloat16* gA[NC];
    const __hip_bfloat16* gB[NC];
#pragma unroll
    for (int q0 = 0; q0 < NC; ++q0) {
        int q = tid + 256 * q0;
        int row = q / CPR;
        int c = (q % CPR) ^ SWZ64(row);
        gA[q0] = A + batch * sA + (long long)(m0 + row) * lda + k0 + c * 8;
        gB[q0] = A + batch * sA + (long long)(n0 + row) * lda + k0 + c * 8;
    }
    floatx4 acc[2][2] = {};
    const int nK = kLen / BKT;

#pragma unroll
    for (int q0 = 0; q0 < NC; ++q0) {
        load_lds16(gA[q0], As + (tid + 256 * q0) * 8);
        load_lds16(gB[q0], Bs + (tid + 256 * q0) * 8);
        gA[q0] += BKT; gB[q0] += BKT;
    }

    int cur = 0;
    for (int kt = 0; kt < nK; ++kt) {
        if (kt + 1 < nK) {
            const int off = (cur ^ 1) * LSZ;
#pragma unroll
            for (int q0 = 0; q0 < NC; ++q0) {
                load_lds16(gA[q0], As + off + (tid + 256 * q0) * 8);
                load_lds16(gB[q0], Bs + off + (tid + 256 * q0) * 8);
                gA[q0] += BKT; gB[q0] += BKT;
            }
            asm volatile("s_waitcnt vmcnt(4)" ::: "memory");
        } else {
            asm volatile("s_waitcnt vmcnt(0)" ::: "memory");
        }
        __builtin_amdgcn_s_barrier();
        const __hip_bfloat16* Ac = As + cur * LSZ;
        const __hip_bfloat16* Bc = Bs + cur * LSZ;
#pragma unroll
        for (int kk = 0; kk < BKT / 32; ++kk) {
            const int cidx = kk * 4 + hi;
            bf16x8 af[2], bfr[2];
#pragma unroll
            for (int i = 0; i < 2; ++i) {
                int row = wm + i * 16 + ln;
                af[i] = *(const bf16x8*)(Ac + row * BKT + ((cidx ^ SWZ64(row)) << 3));
            }
#pragma unroll
            for (int j = 0; j < 2; ++j) {
                int row = wn + j * 16 + ln;
                bfr[j] = *(const bf16x8*)(Bc + row * BKT + ((cidx ^ SWZ64(row)) << 3));
            }
#pragma unroll
            for (int i = 0; i < 2; ++i)
#pragma unroll
                for (int j = 0; j < 2; ++j)
                    acc[i][j] = __builtin_amdgcn_mfma_f32_16x16x32_bf16(af[i], bfr[j], acc[i][j], 0, 0, 0);
        }
        if (kt + 1 < nK) {
            __builtin_amdgcn_s_barrier();
            cur ^= 1;
        }
    }

    // C/D layout: col = lane&15, row = (lane>>4)*4 + r  [m89-verified]
    __hip_bfloat16* Cb = C + batch * sC + ks * 512;
#pragma unroll
    for (int i = 0; i < 2; ++i) {
        int mb = m0 + wm + i * 16 + hi * 4;
#pragma unroll
        for (int j = 0; j < 2; ++j) {
            int nl = n0 + wn + j * 16 + ln;
            bh4 mv;
            mv.x = __float2bfloat16(acc[i][j][0]);
            mv.y = __float2bfloat16(acc[i][j][1]);
            mv.z = __float2bfloat16(acc[i][j][2]);
            mv.w = __float2bfloat16(acc[i][j][3]);
            Cb[(long long)(mb + 0) * ldc + nl] = mv.x;
            Cb[(long long)(mb + 1) * ldc + nl] = mv.y;
            Cb[(long long)(mb + 2) * ldc + nl] = mv.z;
            Cb[(long long)(mb + 3) * ldc + nl] = mv.w;
            if (mt != nt)
                *(bh4*)&Cb[(long long)nl * ldc + mb] = mv;   // mirrored tile
        }
    }
}

// Small MFMA GEMM, 64x64 tile, BK=64, operands K-contiguous.
// MODE 5: plain bf16 store.
// MODE 6: bf16 store of (acc + u[m]·sq[b][n] + ps[b][m]·r[n])/N + u[m]·r[n]
//         + IDENTITY on the diagonal (residual x folded into A2).
// Counted-vmcnt double-buffered K-loop.
template<int MODE>
__global__ __launch_bounds__(256)
void mfma_sm(const __hip_bfloat16* __restrict__ A, long long sA, int lda,
             const __hip_bfloat16* __restrict__ B, long long sB, int ldb,
             __hip_bfloat16* __restrict__ C, long long sC, int ldc,
             const float* __restrict__ pu, const float* __restrict__ pr,
             const float* __restrict__ pps, const float* __restrict__ psq,
             int kLen)
{
    constexpr int BKT = 64;
    constexpr int CPR = BKT / 8;
    constexpr int NC = 64 * CPR / 256;
    constexpr int LSZ = 64 * BKT;
    __shared__ __hip_bfloat16 As[2 * LSZ];
    __shared__ __hip_bfloat16 Bs[2 * LSZ];
    const int tid = threadIdx.x;
    const int lane = tid & 63;
    const int w = tid >> 6;
    const int wm = (w >> 1) << 5;
    const int wn = (w & 1) << 5;
    const int ln = lane & 15;
    const int hi = lane >> 4;
    const int batch = blockIdx.x;
    const int m0 = blockIdx.z << 6;
    const int n0 = blockIdx.y << 6;

    const __hip_bfloat16* gA[NC];
    const __hip_bfloat16* gB[NC];
#pragma unroll
    for (int q0 = 0; q0 < NC; ++q0) {
        int q = tid + 256 * q0;
        int row = q / CPR;
        int c = (q % CPR) ^ SWZ64(row);
        gA[q0] = A + batch * sA + (long long)(m0 + row) * lda + c * 8;
        gB[q0] = B + batch * sB + (long long)(n0 + row) * ldb + c * 8;
    }
    floatx4 acc[2][2] = {};
    const int nK = kLen / BKT;

#pragma unroll
    for (int q0 = 0; q0 < NC; ++q0) {
        load_lds16(gA[q0], As + (tid + 256 * q0) * 8);
        load_lds16(gB[q0], Bs + (tid + 256 * q0) * 8);
        gA[q0] += BKT; gB[q0] += BKT;
    }

    int cur = 0;
    for (int kt = 0; kt < nK; ++kt) {
        if (kt + 1 < nK) {
            const int off = (cur ^ 1) * LSZ;
#pragma unroll
            for (int q0 = 0; q0 < NC; ++q0) {
                load_lds16(gA[q0], As + off + (tid + 256 * q0) * 8);
                load_lds16(gB[q0], Bs + off + (tid + 256 * q0) * 8);
                gA[q0] += BKT; gB[q0] += BKT;
            }
            asm volatile("s_waitcnt vmcnt(4)" ::: "memory");
        } else {
            asm volatile("s_waitcnt vmcnt(0)" ::: "memory");
        }
        __builtin_amdgcn_s_barrier();
        const __hip_bfloat16* Ac = As + cur * LSZ;
        const __hip_bfloat16* Bc = Bs + cur * LSZ;
#pragma unroll
        for (int kk = 0; kk < BKT / 32; ++kk) {
            const int cidx = kk * 4 + hi;
            bf16x8 af[2], bfr[2];
#pragma unroll
            for (int i = 0; i < 2; ++i) {
                int row = wm + i * 16 + ln;
                af[i] = *(const bf16x8*)(Ac + row * BKT + ((cidx ^ SWZ64(row)) << 3));
            }
#pragma unroll
            for (int j = 0; j < 2; ++j) {
                int row = wn + j * 16 + ln;
                bfr[j] = *(const bf16x8*)(Bc + row * BKT + ((cidx ^ SWZ64(row)) << 3));
            }
#pragma unroll
            for (int i = 0; i < 2; ++i)
#pragma unroll
                for (int j = 0; j < 2; ++j)
                    acc[i][j] = __builtin_amdgcn_mfma_f32_16x16x32_bf16(af[i], bfr[j], acc[i][j], 0, 0, 0);
        }
        if (kt + 1 < nK) {
            __builtin_amdgcn_s_barrier();
            cur ^= 1;
        }
    }

    __hip_bfloat16* Cb = C + batch * sC;
#pragma unroll
    for (int i = 0; i < 2; ++i) {
        int mb = m0 + wm + i * 16 + hi * 4;
#pragma unroll
        for (int r = 0; r < 4; ++r) {
#pragma unroll
            for (int j = 0; j < 2; ++j) {
                int nl = n0 + wn + j * 16 + ln;
                float v = acc[i][j][r];
                if (MODE == 6) {
                    float uu = pu[mb + r], rr = pr[nl];
                    v = (v + uu * psq[batch * 512 + nl] + pps[batch * 512 + mb + r] * rr)
                        * (1.f / 3136.f) + uu * rr;
                    if (mb + r == nl) v += 1.f;   // residual fold: A2 += I
                }
                Cb[(long long)(mb + r) * ldc + nl] = __float2bfloat16(v);
            }
        }
    }
}

// B-side swizzle for the transpose-scatter LDS tile: granule ^= SWZ_B(n).
#define SWZB(nr) (((nr) & 7) ^ (((nr) >> 3) & 7))

// Final MFMA GEMM: 64(M)x128(N) tile, 4 waves (64x32 each), BK=64.
// A (A2b) staged via global_load_lds. B staged FROM xnp [c][n] via reg-load +
// ds_write_b16 transpose-scatter with SWZB granule swizzle (R7-verified, 43us).
__global__ __launch_bounds__(256)
void mfma64(const __hip_bfloat16* __restrict__ A, long long sA, int lda,
            const __hip_bfloat16* __restrict__ Bn, long long sB, int ldb,
            float* __restrict__ C, long long sC, int ldc,
            const float* __restrict__ bias, int sBias,
            int kLen, int Nreal)
{
    constexpr int BKT = 64;
    constexpr int CPR = BKT / 8;
    constexpr int NA = 64 * CPR / 256;      // 2 A-loads/thread
    __shared__ __hip_bfloat16 As[64 * BKT];              // 8 KB
    __shared__ __align__(16) short Bs[128 * 64];         // 16 KB, [n][c] swizzled
    const int tid = threadIdx.x;
    const int lane = tid & 63;
    const int w = tid >> 6;
    const int ln = lane & 15;
    const int hi = lane >> 4;
    const int batch = blockIdx.x;
    const int m0 = blockIdx.z << 6;
    const int n0 = blockIdx.y << 7;

    const __hip_bfloat16* gA[NA];
#pragma unroll
    for (int q0 = 0; q0 < NA; ++q0) {
        int q = tid + 256 * q0;
        int row = q / CPR;
        int c = (q % CPR) ^ SWZ64(row);
        gA[q0] = A + batch * sA + (long long)(m0 + row) * lda + c * 8;
    }
    // B staging map: bc = c within K-tile (16 rows/wave), bq = n-chunk phase.
    const int bc = tid >> 2;      // 0..63
    const int bq = tid & 3;       // 0..3
    const short* bbase = (const short*)(Bn + batch * sB)
                         + (long long)bc * ldb + n0 + bq * 8;
    const int g = bc >> 3;

    floatx4 acc[4][2] = {};
    const int nK = kLen / BKT;
    for (int kt = 0; kt < nK; ++kt) {
        // B register loads (4 x 16B; lanes 4-per-row -> full 64B lines)
        s16x8 vb[4];
        const short* bp = bbase + (long long)kt * 64 * ldb;
#pragma unroll
        for (int m = 0; m < 4; ++m)
            vb[m] = *(const s16x8*)(bp + m * 32);
        // A async staging
#pragma unroll
        for (int q0 = 0; q0 < NA; ++q0) {
            load_lds16(gA[q0], As + (tid + 256 * q0) * 8);
            gA[q0] += BKT;
        }
        // transpose-scatter B into LDS (compiler inserts the vmcnt for vb)
#pragma unroll
        for (int m = 0; m < 4; ++m) {
            const int nb = (bq + 4 * m) * 8;
#pragma unroll
            for (int k = 0; k < 8; ++k) {
                const int nr = nb + k;
                Bs[nr * 64 + (((g ^ SWZB(nr)) & 7) << 3) + (bc & 7)] = vb[m][k];
            }
        }
        __syncthreads();   // drains A (vmcnt) + B scatter (lgkm)
#pragma unroll
        for (int kk = 0; kk < BKT / 32; ++kk) {
            const int cidx = kk * 4 + hi;
            bf16x8 af[4], bfr[2];
#pragma unroll
            for (int i = 0; i < 4; ++i) {
                int row = i * 16 + ln;
                af[i] = *(const bf16x8*)(As + row * BKT + ((cidx ^ SWZ64(row)) << 3));
            }
#pragma unroll
            for (int j = 0; j < 2; ++j) {
                int row = w * 32 + j * 16 + ln;
                bfr[j] = *(const bf16x8*)((const __hip_bfloat16*)Bs
                          + row * 64 + (((cidx ^ SWZB(row)) & 7) << 3));
            }
#pragma unroll
            for (int i = 0; i < 4; ++i)
#pragma unroll
                for (int j = 0; j < 2; ++j)
                    acc[i][j] = __builtin_amdgcn_mfma_f32_16x16x32_bf16(af[i], bfr[j], acc[i][j], 0, 0, 0);
        }
        __syncthreads();   // LDS fully read -> safe to restage
    }

    float* Cb = C + batch * sC;
#pragma unroll
    for (int i = 0; i < 4; ++i) {
        int mb = m0 + i * 16 + hi * 4;
#pragma unroll
        for (int r = 0; r < 4; ++r) {
            float bb = bias[batch * sBias + mb + r];
#pragma unroll
            for (int j = 0; j < 2; ++j) {
                int nl = n0 + w * 32 + j * 16 + ln;
                if (nl < Nreal) {
                    Cb[(long long)(mb + r) * ldc + nl] = acc[i][j][r] + bb;
                }
            }
        }
    }
}

extern "C" void kernel_launch(void* const* d_in, const int* in_sizes, int n_in,
                              void* d_out, int out_size, void* d_ws, size_t ws_size,
                              hipStream_t stream)
{
    const float* x  = (const float*)d_in[0];
    const float* wq = (const float*)d_in[1];
    const float* bq = (const float*)d_in[2];
    const float* wk = (const float*)d_in[3];
    const float* bk = (const float*)d_in[4];
    const float* wv = (const float*)d_in[5];
    const float* bv = (const float*)d_in[6];
    const float* wo = (const float*)d_in[7];
    const float* bo = (const float*)d_in[8];
    float* out = (float*)d_out;

    const int N = 3136;
    const long long xs = 512LL * N;               // 1,605,632
    const long long xs2 = 512LL * 3200;           // xnp per-batch stride

    // d_out scratch (dead before the final GEMM overwrites it with out):
    char* ob = (char*)d_out;
    __hip_bfloat16* Gp2 = (__hip_bfloat16*)(ob + 26214400);    // 8x512x1024 bf16 = 8,388,608
    __hip_bfloat16* Tb  = (__hip_bfloat16*)(ob + 34603008);    // 8x512x512 bf16 = 4,194,304

    // ws (~32.05 MB). xnp lives HERE (mfma64 reads it while writing d_out).
    char* wsb = (char*)d_ws;
    __hip_bfloat16* xnp = (__hip_bfloat16*)wsb;                // 26,214,400
    __hip_bfloat16* A2b = (__hip_bfloat16*)(wsb + 26214400);   //  4,194,304
    __hip_bfloat16* Pdb = (__hip_bfloat16*)(wsb + 30408704);   //  1,048,576
    __hip_bfloat16* Qtb = (__hip_bfloat16*)(wsb + 31457280);   //    524,288
    float* sv  = (float*)(wsb + 31981568);                     //     16,384
    float* u_  = (float*)(wsb + 31997952);                     //      2,048
    float* r_  = (float*)(wsb + 32000000);                     //      2,048
    float* w_  = (float*)(wsb + 32002048);                     //      2,048
    float* kap = (float*)(wsb + 32004096);                     //         16
    float* ps  = (float*)(wsb + 32004112);                     //     16,384
    float* sq  = (float*)(wsb + 32020496);                     //     16,384
    float* a2v = (float*)(wsb + 32036880);                     //     16,384

    // 0) zero the rowsum accumulator (stream-ordered)
    hipMemsetAsync(sv, 0, 512 * 8 * sizeof(float), stream);

    // 1) fused: persistent streaming x->xnp + rowsums (800 blocks x 4 tiles,
    //    2-deep prefetch) + weight precompute (bid>=800)
    prep_trans<<<dim3(930, 1, 1), 256, 0, stream>>>(
        x, xnp, sv, wo, wv, wq, wk, bq, bk, bv,
        Pdb, Qtb, u_, r_, w_, kap);

    // 2) Gp2 = partials of X·X^T  (split-K=2, K=1600, BK=64), symmetric
    mfma_g<<<dim3(16, 36), 256, 0, stream>>>(
        xnp, xs2, 3200, Gp2, 524288, 1024, 1600);

    // 3) T = Pd·Gp2  (K=1024 folds the split-K reduce)
    mfma_sm<5><<<dim3(8, 8, 8), 256, 0, stream>>>(
        Pdb, 0, 1024, Gp2, 524288, 1024, Tb, 262144, 512,
        nullptr, nullptr, nullptr, nullptr, 1024);

    // 4) ps = P·s, sq = Qt·s, a2 = [T·w + u(s·w) + ps·κ]/N + uκ + bo
    vec2_kernel<<<1024, 256, 0, stream>>>(Tb, Pdb, Qtb, sv, u_, w_, kap, bo, ps, sq, a2v);

    // 5) A2 = [T·Q + u·sq^T + ps·r^T]/N + u·r^T + I  -> bf16
    mfma_sm<6><<<dim3(8, 8, 8), 256, 0, stream>>>(
        Tb, 262144, 512, Qtb, 0, 512, A2b, 262144, 512,
        u_, r_, ps, sq, 512);

    // 6) out = (A2+I)·X + a2   (M=512, N=3136, K=512), B from xnp via
    //    transpose-scatter staging
    mfma64<<<dim3(8, 25, 8), 256, 0, stream>>>(
        A2b, 262144, 512, xnp, xs2, 3200,
        out, xs, N, a2v, 512, 512, N);
}

// Round 9
// 215.611 us; speedup vs baseline: 1.0005x; 1.0005x over previous
//
#include <hip/hip_runtime.h>
#include <hip/hip_bf16.h>

// DotProductNonLocalBlock: B=8, C=512, N=3136 (pad 3200), E=256.
// No softmax => fully associative. Factored with DATA-INDEPENDENT
// P = wo·wv, Qt = wq^T·wk, u = wo·bv, r = bk^T·wq, w = Wk^T·bq, κ = bk·bq:
//   G  = X·X^T   [bf16 MFMA, split-K=2 col-interleaved partials, SYMMETRIC]
//   T  = Pd·Gp2 (K=1024 folds the reduce)
//   A2 = [T·Q + u·(Qt s)^T + (P s)·r^T]/N + u·r^T + I   (residual folded)
//   a2 = [T·w + u·(s·w) + (P s)·κ]/N + u·κ + bo
//   Out = (A2+I)·X + a2
// LEDGER: final-GEMM: 64x128 single-buf 2-barrier + xnp transpose-scatter B = best
//   (43us). T4 counted-vmcnt on 2-phase loops: neutral. Identity-fold: +16us win.
// R8 lesson (occupancy arithmetic): streaming path finishes in ~10us; the ~44us
//   constant across R5-R8 is the WEIGHT GEMM path (naive fp32 LDS GEMM, 128
//   blocks = 1/CU on half the chip, global load issued AFTER previous compute ->
//   full latency exposed 16x/block). Four streaming rebuilds were tuning the
//   non-critical path.
// R9: weight path software-pipelined — k0+16's float4s prefetched into regs
//   BEFORE compute(k0); latency hides under the ~2K-cyc FMA block. Streaming
//   path / MFMA kernels / launches untouched.

typedef __attribute__((ext_vector_type(8))) __bf16 bf16x8;
typedef __attribute__((ext_vector_type(8))) short s16x8;
typedef __attribute__((ext_vector_type(4))) float floatx4;

struct __align__(8) bh4 { __hip_bfloat16 x, y, z, w; };
struct __align__(16) bh8 { __hip_bfloat16 h[8]; };

__device__ __forceinline__ void load_lds16(const void* g, void* l) {
    __builtin_amdgcn_global_load_lds((const __attribute__((address_space(1))) void*)g,
                                     (__attribute__((address_space(3))) void*)l, 16, 0, 0);
}

// tile id -> (batch, c-block, n-block) for the streaming path (8*8*50 = 3200)
__device__ __forceinline__ void tile_coords(int tile, int& b, int& c0, int& n0) {
    b = tile / 400;
    int rem = tile - b * 400;
    c0 = (rem / 50) << 6;
    n0 = (rem % 50) << 6;
}

__device__ __forceinline__ void load_tile(const float* __restrict__ x, int tile,
                                          int nch, int cr, float4 (&vv)[2][2]) {
    int b, c0, n0; tile_coords(tile, b, c0, n0);
    const float* xb = x + (long long)b * 512 * 3136;
    int nn = n0 + nch * 8;
    if (nn >= 3136) nn = 3128;                  // clamp (pad tiles zeroed at store)
#pragma unroll
    for (int p = 0; p < 2; ++p) {
        const float* xr = xb + (long long)(c0 + cr + 32 * p) * 3136 + nn;
        vv[p][0] = *(const float4*)xr;
        vv[p][1] = *(const float4*)(xr + 4);
    }
}

__device__ __forceinline__ void proc_tile(__hip_bfloat16* __restrict__ xnp,
                                          float* __restrict__ s, int tile,
                                          int nch, int cr, float4 (&vv)[2][2]) {
    int b, c0, n0; tile_coords(tile, b, c0, n0);
    __hip_bfloat16* xno = xnp + (long long)b * 512 * 3200;
    const bool pad = (n0 >= 3136);
    float rsum[2];
#pragma unroll
    for (int p = 0; p < 2; ++p) {
        float4 v0 = vv[p][0], v1 = vv[p][1];
        if (pad) {
            v0 = make_float4(0.f, 0.f, 0.f, 0.f);
            v1 = make_float4(0.f, 0.f, 0.f, 0.f);
        }
        bh8 o;
        o.h[0] = __float2bfloat16(v0.x); o.h[1] = __float2bfloat16(v0.y);
        o.h[2] = __float2bfloat16(v0.z); o.h[3] = __float2bfloat16(v0.w);
        o.h[4] = __float2bfloat16(v1.x); o.h[5] = __float2bfloat16(v1.y);
        o.h[6] = __float2bfloat16(v1.z); o.h[7] = __float2bfloat16(v1.w);
        *(bh8*)&xno[(long long)(c0 + cr + 32 * p) * 3200 + n0 + nch * 8] = o;
        float rs = v0.x + v0.y + v0.z + v0.w + v1.x + v1.y + v1.z + v1.w;
        rs += __shfl_xor(rs, 1, 8);
        rs += __shfl_xor(rs, 2, 8);
        rs += __shfl_xor(rs, 4, 8);
        rsum[p] = rs;
    }
    if (!pad && nch == 0) {
        atomicAdd(&s[b * 512 + c0 + cr], rsum[0]);
        atomicAdd(&s[b * 512 + c0 + cr + 32], rsum[1]);
    }
}

// ---- fused: x->xnp streaming convert (persistent) + data-independent precompute ----
// bid <  800: streaming path, tiles {bid, bid+800, bid+1600, bid+2400},
//             2-deep register prefetch pipeline.
// bid >= 800: blk = bid-800:
//   blk in [0,64)   -> Pd tile (P = wo·wv, duplicated [P|P])   [sw-pipelined]
//   blk in [64,128) -> Qt tile (wq^T·wk)                        [sw-pipelined]
//   blk 128,129     -> u/r/w vectors (256 channels each)
__global__ __launch_bounds__(256)
void prep_trans(const float* __restrict__ x, __hip_bfloat16* __restrict__ xnp,
                float* __restrict__ s,
                const float* __restrict__ wo, const float* __restrict__ wv,
                const float* __restrict__ wq, const float* __restrict__ wk,
                const float* __restrict__ bq, const float* __restrict__ bk,
                const float* __restrict__ bv,
                __hip_bfloat16* __restrict__ Pdb, __hip_bfloat16* __restrict__ Qtb,
                float* __restrict__ u, float* __restrict__ r, float* __restrict__ w,
                float* __restrict__ kap)
{
    __shared__ __align__(16) float smem[2 * 16 * 68];   // 8.7KB, weight path only
    const int tid = threadIdx.x;
    const int bid = blockIdx.x;

    if (bid >= 800) {
        // ---------- weight path ----------
        const int blk = bid - 800;
        if (blk >= 130) return;
        if (blk >= 128) {
            int c = (blk - 128) * 256 + tid;
            float su = 0.f, sr = 0.f, sw = 0.f;
            for (int e = 0; e < 256; ++e) {
                su = fmaf(wo[(long long)c * 256 + e], bv[e], su);
                sr = fmaf(bk[e], wq[(long long)e * 512 + c], sr);
                sw = fmaf(wk[(long long)e * 512 + c], bq[e], sw);
            }
            u[c] = su; r[c] = sr; w[c] = sw;
            if (c == 0) {
                float k2 = 0.f;
                for (int e = 0; e < 256; ++e) k2 = fmaf(bk[e], bq[e], k2);
                *kap = k2;
            }
            return;
        }
        const bool doQ = (blk >= 64);
        const int tt = blk & 63;
        const int m0 = (tt >> 3) * 64, n0 = (tt & 7) * 64;
        float (*As)[68] = (float(*)[68])smem;
        float (*Bs)[68] = (float(*)[68])(smem + 16 * 68);
        const int tx = tid & 15, ty = tid >> 4;
        const int lk = tid >> 4, lc = (tid & 15) * 4;
        const int lr = tid >> 2, lk4 = (tid & 3) * 4;
        float acc[4][4] = {};

        // software pipeline: regs hold chunk k0; next chunk's loads issued
        // BEFORE compute(k0) so global latency hides under the FMA block.
        float4 av, bv4, nav, nbv;
        if (doQ) {
            av  = *(const float4*)&wq[0 * 512 + (long long)lk * 512 + m0 + lc];
            bv4 = *(const float4*)&wk[(long long)lk * 512 + n0 + lc];
        } else {
            av  = *(const float4*)&wo[(long long)(m0 + lr) * 256 + lk4];
            bv4 = *(const float4*)&wv[(long long)lk * 512 + n0 + lc];
        }
        for (int k0 = 0; k0 < 256; k0 += 16) {
            __syncthreads();                 // all waves done reading As/Bs
            if (doQ) {
                *(float4*)&As[lk][lc] = av;
            } else {
                As[lk4 + 0][lr] = av.x; As[lk4 + 1][lr] = av.y;
                As[lk4 + 2][lr] = av.z; As[lk4 + 3][lr] = av.w;
            }
            *(float4*)&Bs[lk][lc] = bv4;
            __syncthreads();
            if (k0 + 16 < 256) {             // prefetch next chunk (pre-compute)
                if (doQ) {
                    nav = *(const float4*)&wq[(long long)(k0 + 16 + lk) * 512 + m0 + lc];
                    nbv = *(const float4*)&wk[(long long)(k0 + 16 + lk) * 512 + n0 + lc];
                } else {
                    nav = *(const float4*)&wo[(long long)(m0 + lr) * 256 + k0 + 16 + lk4];
                    nbv = *(const float4*)&wv[(long long)(k0 + 16 + lk) * 512 + n0 + lc];
                }
            }
#pragma unroll
            for (int kk = 0; kk < 16; ++kk) {
                float a[4], b[4];
#pragma unroll
                for (int i = 0; i < 4; ++i) { a[i] = As[kk][ty * 4 + i]; b[i] = Bs[kk][tx * 4 + i]; }
#pragma unroll
                for (int i = 0; i < 4; ++i)
#pragma unroll
                    for (int j = 0; j < 4; ++j) acc[i][j] = fmaf(a[i], b[j], acc[i][j]);
            }
            av = nav; bv4 = nbv;
        }
        const int mo = m0 + ty * 4, no = n0 + tx * 4;
        if (doQ) {
#pragma unroll
            for (int i = 0; i < 4; ++i)
#pragma unroll
                for (int j = 0; j < 4; ++j)
                    Qtb[(long long)(mo + i) * 512 + no + j] = __float2bfloat16(acc[i][j]);
        } else {
#pragma unroll
            for (int i = 0; i < 4; ++i)
#pragma unroll
                for (int j = 0; j < 4; ++j) {
                    __hip_bfloat16 v = __float2bfloat16(acc[i][j]);
                    Pdb[(long long)(mo + i) * 1024 + no + j] = v;
                    Pdb[(long long)(mo + i) * 1024 + no + j + 512] = v;
                }
        }
        return;
    }

    // ---------- streaming path: 4 tiles, 2-deep register prefetch ----------
    const int nch = tid & 7;      // 8-float chunk within 64-n tile
    const int cr  = tid >> 3;     // 0..31
    float4 va[2][2], vb[2][2];    // static double-buffer (no runtime indexing)

    load_tile(x, bid,        nch, cr, va);
    load_tile(x, bid + 800,  nch, cr, vb);
    proc_tile(xnp, s, bid,        nch, cr, va);
    load_tile(x, bid + 1600, nch, cr, va);
    proc_tile(xnp, s, bid + 800,  nch, cr, vb);
    load_tile(x, bid + 2400, nch, cr, vb);
    proc_tile(xnp, s, bid + 1600, nch, cr, va);
    proc_tile(xnp, s, bid + 2400, nch, cr, vb);
}

// Wave-per-output: ps = P·s, sq = Qt·s, a2 = [T·w + u(s·w) + ps·κ]/N + uκ + bo.
__global__ __launch_bounds__(256)
void vec2_kernel(const __hip_bfloat16* __restrict__ T, const __hip_bfloat16* __restrict__ Pdb,
                 const __hip_bfloat16* __restrict__ Qtb, const float* __restrict__ s,
                 const float* __restrict__ u, const float* __restrict__ w,
                 const float* __restrict__ kap, const float* __restrict__ bo,
                 float* __restrict__ ps, float* __restrict__ sq, float* __restrict__ a2)
{
    const int idx = blockIdx.x * 4 + (threadIdx.x >> 6);   // b*512+c
    const int lane = threadIdx.x & 63;
    const int b = idx >> 9, c = idx & 511;
    const int j0 = lane * 8;
    const float* sb = s + b * 512;
    float4 s0 = *(const float4*)&sb[j0], s1 = *(const float4*)&sb[j0 + 4];
    float4 w0 = *(const float4*)&w[j0],  w1 = *(const float4*)&w[j0 + 4];
    bf16x8 pv = *(const bf16x8*)&Pdb[(long long)c * 1024 + j0];
    bf16x8 qv = *(const bf16x8*)&Qtb[(long long)c * 512 + j0];
    bf16x8 tv = *(const bf16x8*)&T[(long long)b * 262144 + (long long)c * 512 + j0];
    float sj[8] = {s0.x, s0.y, s0.z, s0.w, s1.x, s1.y, s1.z, s1.w};
    float wj[8] = {w0.x, w0.y, w0.z, w0.w, w1.x, w1.y, w1.z, w1.w};
    float aps = 0.f, asq = 0.f, atw = 0.f, asw = 0.f;
#pragma unroll
    for (int t = 0; t < 8; ++t) {
        aps = fmaf((float)pv[t], sj[t], aps);
        asq = fmaf((float)qv[t], sj[t], asq);
        atw = fmaf((float)tv[t], wj[t], atw);
        asw = fmaf(sj[t], wj[t], asw);
    }
#pragma unroll
    for (int m = 1; m < 64; m <<= 1) {
        aps += __shfl_xor(aps, m);
        asq += __shfl_xor(asq, m);
        atw += __shfl_xor(atw, m);
        asw += __shfl_xor(asw, m);
    }
    if (lane == 0) {
        ps[idx] = aps; sq[idx] = asq;
        float kp = *kap;
        a2[idx] = (atw + u[c] * asw + aps * kp) * (1.f / 3136.f) + u[c] * kp + bo[c];
    }
}

#define SWZ64(row) ((row) & 7)

// G GEMM with symmetric mirroring. 64x64 tile, BK=64, operands = xnp (both).
// Grid: x = batch + 8*ks (XCD affinity), y = triangular pair index (36).
// Counted-vmcnt double-buffered K-loop.
__global__ __launch_bounds__(256)
void mfma_g(const __hip_bfloat16* __restrict__ A, long long sA, int lda,
            __hip_bfloat16* __restrict__ C, long long sC, int ldc,
            int kLen)
{
    constexpr int BKT = 64;
    constexpr int CPR = BKT / 8;
    constexpr int NC = 64 * CPR / 256;
    constexpr int LSZ = 64 * BKT;
    __shared__ __hip_bfloat16 As[2 * LSZ];
    __shared__ __hip_bfloat16 Bs[2 * LSZ];
    const int tid = threadIdx.x;
    const int lane = tid & 63;
    const int w = tid >> 6;
    const int wm = (w >> 1) << 5;
    const int wn = (w & 1) << 5;
    const int ln = lane & 15;
    const int hi = lane >> 4;
    const int bx = blockIdx.x;
    const int batch = bx & 7, ks = bx >> 3;
    int p = blockIdx.y, mt = 0;
    while (p >= 8 - mt) { p -= 8 - mt; ++mt; }
    const int nt = mt + p;
    const int m0 = mt << 6, n0 = nt << 6;
    const long long k0 = (long long)ks * kLen;

    const __hip_bfloat16* gA[NC];
    const __hip_bfloat16* gB[NC];
#pragma unroll
    for (int q0 = 0; q0 < NC; ++q0) {
        int q = tid + 256 * q0;
        int row = q / CPR;
        int c = (q % CPR) ^ SWZ64(row);
        gA[q0] = A + batch * sA + (long long)(m0 + row) * lda + k0 + c * 8;
        gB[q0] = A + batch * sA + (long long)(n0 + row) * lda + k0 + c * 8;
    }
    floatx4 acc[2][2] = {};
    const int nK = kLen / BKT;

#pragma unroll
    for (int q0 = 0; q0 < NC; ++q0) {
        load_lds16(gA[q0], As + (tid + 256 * q0) * 8);
        load_lds16(gB[q0], Bs + (tid + 256 * q0) * 8);
        gA[q0] += BKT; gB[q0] += BKT;
    }

    int cur = 0;
    for (int kt = 0; kt < nK; ++kt) {
        if (kt + 1 < nK) {
            const int off = (cur ^ 1) * LSZ;
#pragma unroll
            for (int q0 = 0; q0 < NC; ++q0) {
                load_lds16(gA[q0], As + off + (tid + 256 * q0) * 8);
                load_lds16(gB[q0], Bs + off + (tid + 256 * q0) * 8);
                gA[q0] += BKT; gB[q0] += BKT;
            }
            asm volatile("s_waitcnt vmcnt(4)" ::: "memory");
        } else {
            asm volatile("s_waitcnt vmcnt(0)" ::: "memory");
        }
        __builtin_amdgcn_s_barrier();
        const __hip_bfloat16* Ac = As + cur * LSZ;
        const __hip_bfloat16* Bc = Bs + cur * LSZ;
#pragma unroll
        for (int kk = 0; kk < BKT / 32; ++kk) {
            const int cidx = kk * 4 + hi;
            bf16x8 af[2], bfr[2];
#pragma unroll
            for (int i = 0; i < 2; ++i) {
                int row = wm + i * 16 + ln;
                af[i] = *(const bf16x8*)(Ac + row * BKT + ((cidx ^ SWZ64(row)) << 3));
            }
#pragma unroll
            for (int j = 0; j < 2; ++j) {
                int row = wn + j * 16 + ln;
                bfr[j] = *(const bf16x8*)(Bc + row * BKT + ((cidx ^ SWZ64(row)) << 3));
            }
#pragma unroll
            for (int i = 0; i < 2; ++i)
#pragma unroll
                for (int j = 0; j < 2; ++j)
                    acc[i][j] = __builtin_amdgcn_mfma_f32_16x16x32_bf16(af[i], bfr[j], acc[i][j], 0, 0, 0);
        }
        if (kt + 1 < nK) {
            __builtin_amdgcn_s_barrier();
            cur ^= 1;
        }
    }

    // C/D layout: col = lane&15, row = (lane>>4)*4 + r  [m89-verified]
    __hip_bfloat16* Cb = C + batch * sC + ks * 512;
#pragma unroll
    for (int i = 0; i < 2; ++i) {
        int mb = m0 + wm + i * 16 + hi * 4;
#pragma unroll
        for (int j = 0; j < 2; ++j) {
            int nl = n0 + wn + j * 16 + ln;
            bh4 mv;
            mv.x = __float2bfloat16(acc[i][j][0]);
            mv.y = __float2bfloat16(acc[i][j][1]);
            mv.z = __float2bfloat16(acc[i][j][2]);
            mv.w = __float2bfloat16(acc[i][j][3]);
            Cb[(long long)(mb + 0) * ldc + nl] = mv.x;
            Cb[(long long)(mb + 1) * ldc + nl] = mv.y;
            Cb[(long long)(mb + 2) * ldc + nl] = mv.z;
            Cb[(long long)(mb + 3) * ldc + nl] = mv.w;
            if (mt != nt)
                *(bh4*)&Cb[(long long)nl * ldc + mb] = mv;   // mirrored tile
        }
    }
}

// Small MFMA GEMM, 64x64 tile, BK=64, operands K-contiguous.
// MODE 5: plain bf16 store.
// MODE 6: bf16 store of (acc + u[m]·sq[b][n] + ps[b][m]·r[n])/N + u[m]·r[n]
//         + IDENTITY on the diagonal (residual x folded into A2).
// Counted-vmcnt double-buffered K-loop.
template<int MODE>
__global__ __launch_bounds__(256)
void mfma_sm(const __hip_bfloat16* __restrict__ A, long long sA, int lda,
             const __hip_bfloat16* __restrict__ B, long long sB, int ldb,
             __hip_bfloat16* __restrict__ C, long long sC, int ldc,
             const float* __restrict__ pu, const float* __restrict__ pr,
             const float* __restrict__ pps, const float* __restrict__ psq,
             int kLen)
{
    constexpr int BKT = 64;
    constexpr int CPR = BKT / 8;
    constexpr int NC = 64 * CPR / 256;
    constexpr int LSZ = 64 * BKT;
    __shared__ __hip_bfloat16 As[2 * LSZ];
    __shared__ __hip_bfloat16 Bs[2 * LSZ];
    const int tid = threadIdx.x;
    const int lane = tid & 63;
    const int w = tid >> 6;
    const int wm = (w >> 1) << 5;
    const int wn = (w & 1) << 5;
    const int ln = lane & 15;
    const int hi = lane >> 4;
    const int batch = blockIdx.x;
    const int m0 = blockIdx.z << 6;
    const int n0 = blockIdx.y << 6;

    const __hip_bfloat16* gA[NC];
    const __hip_bfloat16* gB[NC];
#pragma unroll
    for (int q0 = 0; q0 < NC; ++q0) {
        int q = tid + 256 * q0;
        int row = q / CPR;
        int c = (q % CPR) ^ SWZ64(row);
        gA[q0] = A + batch * sA + (long long)(m0 + row) * lda + c * 8;
        gB[q0] = B + batch * sB + (long long)(n0 + row) * ldb + c * 8;
    }
    floatx4 acc[2][2] = {};
    const int nK = kLen / BKT;

#pragma unroll
    for (int q0 = 0; q0 < NC; ++q0) {
        load_lds16(gA[q0], As + (tid + 256 * q0) * 8);
        load_lds16(gB[q0], Bs + (tid + 256 * q0) * 8);
        gA[q0] += BKT; gB[q0] += BKT;
    }

    int cur = 0;
    for (int kt = 0; kt < nK; ++kt) {
        if (kt + 1 < nK) {
            const int off = (cur ^ 1) * LSZ;
#pragma unroll
            for (int q0 = 0; q0 < NC; ++q0) {
                load_lds16(gA[q0], As + off + (tid + 256 * q0) * 8);
                load_lds16(gB[q0], Bs + off + (tid + 256 * q0) * 8);
                gA[q0] += BKT; gB[q0] += BKT;
            }
            asm volatile("s_waitcnt vmcnt(4)" ::: "memory");
        } else {
            asm volatile("s_waitcnt vmcnt(0)" ::: "memory");
        }
        __builtin_amdgcn_s_barrier();
        const __hip_bfloat16* Ac = As + cur * LSZ;
        const __hip_bfloat16* Bc = Bs + cur * LSZ;
#pragma unroll
        for (int kk = 0; kk < BKT / 32; ++kk) {
            const int cidx = kk * 4 + hi;
            bf16x8 af[2], bfr[2];
#pragma unroll
            for (int i = 0; i < 2; ++i) {
                int row = wm + i * 16 + ln;
                af[i] = *(const bf16x8*)(Ac + row * BKT + ((cidx ^ SWZ64(row)) << 3));
            }
#pragma unroll
            for (int j = 0; j < 2; ++j) {
                int row = wn + j * 16 + ln;
                bfr[j] = *(const bf16x8*)(Bc + row * BKT + ((cidx ^ SWZ64(row)) << 3));
            }
#pragma unroll
            for (int i = 0; i < 2; ++i)
#pragma unroll
                for (int j = 0; j < 2; ++j)
                    acc[i][j] = __builtin_amdgcn_mfma_f32_16x16x32_bf16(af[i], bfr[j], acc[i][j], 0, 0, 0);
        }
        if (kt + 1 < nK) {
            __builtin_amdgcn_s_barrier();
            cur ^= 1;
        }
    }

    __hip_bfloat16* Cb = C + batch * sC;
#pragma unroll
    for (int i = 0; i < 2; ++i) {
        int mb = m0 + wm + i * 16 + hi * 4;
#pragma unroll
        for (int r = 0; r < 4; ++r) {
#pragma unroll
            for (int j = 0; j < 2; ++j) {
                int nl = n0 + wn + j * 16 + ln;
                float v = acc[i][j][r];
                if (MODE == 6) {
                    float uu = pu[mb + r], rr = pr[nl];
                    v = (v + uu * psq[batch * 512 + nl] + pps[batch * 512 + mb + r] * rr)
                        * (1.f / 3136.f) + uu * rr;
                    if (mb + r == nl) v += 1.f;   // residual fold: A2 += I
                }
                Cb[(long long)(mb + r) * ldc + nl] = __float2bfloat16(v);
            }
        }
    }
}

// B-side swizzle for the transpose-scatter LDS tile: granule ^= SWZ_B(n).
#define SWZB(nr) (((nr) & 7) ^ (((nr) >> 3) & 7))

// Final MFMA GEMM: 64(M)x128(N) tile, 4 waves (64x32 each), BK=64.
// A (A2b) staged via global_load_lds. B staged FROM xnp [c][n] via reg-load +
// ds_write_b16 transpose-scatter with SWZB granule swizzle (R7-verified, 43us).
__global__ __launch_bounds__(256)
void mfma64(const __hip_bfloat16* __restrict__ A, long long sA, int lda,
            const __hip_bfloat16* __restrict__ Bn, long long sB, int ldb,
            float* __restrict__ C, long long sC, int ldc,
            const float* __restrict__ bias, int sBias,
            int kLen, int Nreal)
{
    constexpr int BKT = 64;
    constexpr int CPR = BKT / 8;
    constexpr int NA = 64 * CPR / 256;      // 2 A-loads/thread
    __shared__ __hip_bfloat16 As[64 * BKT];              // 8 KB
    __shared__ __align__(16) short Bs[128 * 64];         // 16 KB, [n][c] swizzled
    const int tid = threadIdx.x;
    const int lane = tid & 63;
    const int w = tid >> 6;
    const int ln = lane & 15;
    const int hi = lane >> 4;
    const int batch = blockIdx.x;
    const int m0 = blockIdx.z << 6;
    const int n0 = blockIdx.y << 7;

    const __hip_bfloat16* gA[NA];
#pragma unroll
    for (int q0 = 0; q0 < NA; ++q0) {
        int q = tid + 256 * q0;
        int row = q / CPR;
        int c = (q % CPR) ^ SWZ64(row);
        gA[q0] = A + batch * sA + (long long)(m0 + row) * lda + c * 8;
    }
    // B staging map: bc = c within K-tile (16 rows/wave), bq = n-chunk phase.
    const int bc = tid >> 2;      // 0..63
    const int bq = tid & 3;       // 0..3
    const short* bbase = (const short*)(Bn + batch * sB)
                         + (long long)bc * ldb + n0 + bq * 8;
    const int g = bc >> 3;

    floatx4 acc[4][2] = {};
    const int nK = kLen / BKT;
    for (int kt = 0; kt < nK; ++kt) {
        // B register loads (4 x 16B; lanes 4-per-row -> full 64B lines)
        s16x8 vb[4];
        const short* bp = bbase + (long long)kt * 64 * ldb;
#pragma unroll
        for (int m = 0; m < 4; ++m)
            vb[m] = *(const s16x8*)(bp + m * 32);
        // A async staging
#pragma unroll
        for (int q0 = 0; q0 < NA; ++q0) {
            load_lds16(gA[q0], As + (tid + 256 * q0) * 8);
            gA[q0] += BKT;
        }
        // transpose-scatter B into LDS (compiler inserts the vmcnt for vb)
#pragma unroll
        for (int m = 0; m < 4; ++m) {
            const int nb = (bq + 4 * m) * 8;
#pragma unroll
            for (int k = 0; k < 8; ++k) {
                const int nr = nb + k;
                Bs[nr * 64 + (((g ^ SWZB(nr)) & 7) << 3) + (bc & 7)] = vb[m][k];
            }
        }
        __syncthreads();   // drains A (vmcnt) + B scatter (lgkm)
#pragma unroll
        for (int kk = 0; kk < BKT / 32; ++kk) {
            const int cidx = kk * 4 + hi;
            bf16x8 af[4], bfr[2];
#pragma unroll
            for (int i = 0; i < 4; ++i) {
                int row = i * 16 + ln;
                af[i] = *(const bf16x8*)(As + row * BKT + ((cidx ^ SWZ64(row)) << 3));
            }
#pragma unroll
            for (int j = 0; j < 2; ++j) {
                int row = w * 32 + j * 16 + ln;
                bfr[j] = *(const bf16x8*)((const __hip_bfloat16*)Bs
                          + row * 64 + (((cidx ^ SWZB(row)) & 7) << 3));
            }
#pragma unroll
            for (int i = 0; i < 4; ++i)
#pragma unroll
                for (int j = 0; j < 2; ++j)
                    acc[i][j] = __builtin_amdgcn_mfma_f32_16x16x32_bf16(af[i], bfr[j], acc[i][j], 0, 0, 0);
        }
        __syncthreads();   // LDS fully read -> safe to restage
    }

    float* Cb = C + batch * sC;
#pragma unroll
    for (int i = 0; i < 4; ++i) {
        int mb = m0 + i * 16 + hi * 4;
#pragma unroll
        for (int r = 0; r < 4; ++r) {
            float bb = bias[batch * sBias + mb + r];
#pragma unroll
            for (int j = 0; j < 2; ++j) {
                int nl = n0 + w * 32 + j * 16 + ln;
                if (nl < Nreal) {
                    Cb[(long long)(mb + r) * ldc + nl] = acc[i][j][r] + bb;
                }
            }
        }
    }
}

extern "C" void kernel_launch(void* const* d_in, const int* in_sizes, int n_in,
                              void* d_out, int out_size, void* d_ws, size_t ws_size,
                              hipStream_t stream)
{
    const float* x  = (const float*)d_in[0];
    const float* wq = (const float*)d_in[1];
    const float* bq = (const float*)d_in[2];
    const float* wk = (const float*)d_in[3];
    const float* bk = (const float*)d_in[4];
    const float* wv = (const float*)d_in[5];
    const float* bv = (const float*)d_in[6];
    const float* wo = (const float*)d_in[7];
    const float* bo = (const float*)d_in[8];
    float* out = (float*)d_out;

    const int N = 3136;
    const long long xs = 512LL * N;               // 1,605,632
    const long long xs2 = 512LL * 3200;           // xnp per-batch stride

    // d_out scratch (dead before the final GEMM overwrites it with out):
    char* ob = (char*)d_out;
    __hip_bfloat16* Gp2 = (__hip_bfloat16*)(ob + 26214400);    // 8x512x1024 bf16 = 8,388,608
    __hip_bfloat16* Tb  = (__hip_bfloat16*)(ob + 34603008);    // 8x512x512 bf16 = 4,194,304

    // ws (~32.05 MB). xnp lives HERE (mfma64 reads it while writing d_out).
    char* wsb = (char*)d_ws;
    __hip_bfloat16* xnp = (__hip_bfloat16*)wsb;                // 26,214,400
    __hip_bfloat16* A2b = (__hip_bfloat16*)(wsb + 26214400);   //  4,194,304
    __hip_bfloat16* Pdb = (__hip_bfloat16*)(wsb + 30408704);   //  1,048,576
    __hip_bfloat16* Qtb = (__hip_bfloat16*)(wsb + 31457280);   //    524,288
    float* sv  = (float*)(wsb + 31981568);                     //     16,384
    float* u_  = (float*)(wsb + 31997952);                     //      2,048
    float* r_  = (float*)(wsb + 32000000);                     //      2,048
    float* w_  = (float*)(wsb + 32002048);                     //      2,048
    float* kap = (float*)(wsb + 32004096);                     //         16
    float* ps  = (float*)(wsb + 32004112);                     //     16,384
    float* sq  = (float*)(wsb + 32020496);                     //     16,384
    float* a2v = (float*)(wsb + 32036880);                     //     16,384

    // 0) zero the rowsum accumulator (stream-ordered)
    hipMemsetAsync(sv, 0, 512 * 8 * sizeof(float), stream);

    // 1) fused: persistent streaming x->xnp + rowsums (800 blocks x 4 tiles)
    //    + weight precompute (bid>=800, software-pipelined)
    prep_trans<<<dim3(930, 1, 1), 256, 0, stream>>>(
        x, xnp, sv, wo, wv, wq, wk, bq, bk, bv,
        Pdb, Qtb, u_, r_, w_, kap);

    // 2) Gp2 = partials of X·X^T  (split-K=2, K=1600, BK=64), symmetric
    mfma_g<<<dim3(16, 36), 256, 0, stream>>>(
        xnp, xs2, 3200, Gp2, 524288, 1024, 1600);

    // 3) T = Pd·Gp2  (K=1024 folds the split-K reduce)
    mfma_sm<5><<<dim3(8, 8, 8), 256, 0, stream>>>(
        Pdb, 0, 1024, Gp2, 524288, 1024, Tb, 262144, 512,
        nullptr, nullptr, nullptr, nullptr, 1024);

    // 4) ps = P·s, sq = Qt·s, a2 = [T·w + u(s·w) + ps·κ]/N + uκ + bo
    vec2_kernel<<<1024, 256, 0, stream>>>(Tb, Pdb, Qtb, sv, u_, w_, kap, bo, ps, sq, a2v);

    // 5) A2 = [T·Q + u·sq^T + ps·r^T]/N + u·r^T + I  -> bf16
    mfma_sm<6><<<dim3(8, 8, 8), 256, 0, stream>>>(
        Tb, 262144, 512, Qtb, 0, 512, A2b, 262144, 512,
        u_, r_, ps, sq, 512);

    // 6) out = (A2+I)·X + a2   (M=512, N=3136, K=512), B from xnp via
    //    transpose-scatter staging
    mfma64<<<dim3(8, 25, 8), 256, 0, stream>>>(
        A2b, 262144, 512, xnp, xs2, 3200,
        out, xs, N, a2v, 512, 512, N);
}

// Round 10
// 209.369 us; speedup vs baseline: 1.0303x; 1.0298x over previous
//
#include <hip/hip_runtime.h>
#include <hip/hip_bf16.h>

// DotProductNonLocalBlock: B=8, C=512, N=3136 (pad 3200), E=256.
// No softmax => fully associative. Factored with DATA-INDEPENDENT
// P = wo·wv, Qt = wq^T·wk, u = wo·bv, r = bk^T·wq, w = Wk^T·bq, κ = bk·bq:
//   G  = X·X^T   [bf16 MFMA, split-K=2 col-interleaved partials, SYMMETRIC]
//   T  = Pd·Gp2 (K=1024 folds the reduce)
//   A2 = [T·Q + u·(Qt s)^T + (P s)·r^T]/N + u·r^T + I   (residual folded)
//   a2 = [T·w + u·(s·w) + (P s)·κ]/N + u·κ + bo
//   Out = (A2+I)·X + a2
// LEDGER: final-GEMM: 64x128 single-buf 2-barrier + xnp transpose-scatter B = best
//   (43us). Identity-fold: +16us. T4 counted-vmcnt on 2-phase: neutral.
// R9 lesson: FIVE streaming/weight rebuilds all null at ~44us; per-path arithmetic
//   says both paths <=12us => cannot localize the straggler while fused.
// R10: (a) SPLIT — conv_x (pure streaming) is its own launch so its duration is
//   directly measurable; (b) weight path (P/Qt/u/r/w, weight-only deps) rides
//   mfma_g's grid as y in [36,45) — complementary pipes (VALU/global vs MFMA/LDS),
//   hidden under G's envelope for free. All weight consumers run after this
//   kernel completes. LDS arena = max(32KB G, 8.7KB weight) = 32KB (unchanged).

typedef __attribute__((ext_vector_type(8))) __bf16 bf16x8;
typedef __attribute__((ext_vector_type(8))) short s16x8;
typedef __attribute__((ext_vector_type(4))) float floatx4;

struct __align__(8) bh4 { __hip_bfloat16 x, y, z, w; };
struct __align__(16) bh8 { __hip_bfloat16 h[8]; };

__device__ __forceinline__ void load_lds16(const void* g, void* l) {
    __builtin_amdgcn_global_load_lds((const __attribute__((address_space(1))) void*)g,
                                     (__attribute__((address_space(3))) void*)l, 16, 0, 0);
}

// ---- pure streaming: x fp32 -> xnp bf16 [512][3200] + rowsums ----
__global__ __launch_bounds__(256)
void conv_x(const float* __restrict__ x, __hip_bfloat16* __restrict__ xnp,
            float* __restrict__ s)
{
    const int b = blockIdx.z;
    const int n0 = blockIdx.x * 64, c0 = blockIdx.y * 64;
    const int tid = threadIdx.x;
    const int nch = tid & 7;      // 8-float chunk within 64-n tile
    const int cr  = tid >> 3;     // 0..31
    __hip_bfloat16* xno = xnp + (long long)b * 512 * 3200;

    if (n0 >= 3136) {             // pad tile: zero xnp cols [3136,3200)
        bh8 z8;
#pragma unroll
        for (int k = 0; k < 8; ++k) z8.h[k] = __float2bfloat16(0.f);
#pragma unroll
        for (int p = 0; p < 2; ++p)
            *(bh8*)&xno[(long long)(c0 + cr + 32 * p) * 3200 + n0 + nch * 8] = z8;
        return;
    }
    const float* xb = x + (long long)b * 512 * 3136;
    float4 v[2][2];
#pragma unroll
    for (int p = 0; p < 2; ++p) {
        const float* xr = xb + (long long)(c0 + cr + 32 * p) * 3136 + n0 + nch * 8;
        v[p][0] = *(const float4*)xr;
        v[p][1] = *(const float4*)(xr + 4);
    }
    float rsum[2];
#pragma unroll
    for (int p = 0; p < 2; ++p) {
        float4 v0 = v[p][0], v1 = v[p][1];
        bh8 o;
        o.h[0] = __float2bfloat16(v0.x); o.h[1] = __float2bfloat16(v0.y);
        o.h[2] = __float2bfloat16(v0.z); o.h[3] = __float2bfloat16(v0.w);
        o.h[4] = __float2bfloat16(v1.x); o.h[5] = __float2bfloat16(v1.y);
        o.h[6] = __float2bfloat16(v1.z); o.h[7] = __float2bfloat16(v1.w);
        *(bh8*)&xno[(long long)(c0 + cr + 32 * p) * 3200 + n0 + nch * 8] = o;
        float rs = v0.x + v0.y + v0.z + v0.w + v1.x + v1.y + v1.z + v1.w;
        rs += __shfl_xor(rs, 1, 8);
        rs += __shfl_xor(rs, 2, 8);
        rs += __shfl_xor(rs, 4, 8);
        rsum[p] = rs;
    }
    if (nch == 0) {
        atomicAdd(&s[b * 512 + c0 + cr], rsum[0]);
        atomicAdd(&s[b * 512 + c0 + cr + 32], rsum[1]);
    }
}

// Wave-per-output: ps = P·s, sq = Qt·s, a2 = [T·w + u(s·w) + ps·κ]/N + uκ + bo.
__global__ __launch_bounds__(256)
void vec2_kernel(const __hip_bfloat16* __restrict__ T, const __hip_bfloat16* __restrict__ Pdb,
                 const __hip_bfloat16* __restrict__ Qtb, const float* __restrict__ s,
                 const float* __restrict__ u, const float* __restrict__ w,
                 const float* __restrict__ kap, const float* __restrict__ bo,
                 float* __restrict__ ps, float* __restrict__ sq, float* __restrict__ a2)
{
    const int idx = blockIdx.x * 4 + (threadIdx.x >> 6);   // b*512+c
    const int lane = threadIdx.x & 63;
    const int b = idx >> 9, c = idx & 511;
    const int j0 = lane * 8;
    const float* sb = s + b * 512;
    float4 s0 = *(const float4*)&sb[j0], s1 = *(const float4*)&sb[j0 + 4];
    float4 w0 = *(const float4*)&w[j0],  w1 = *(const float4*)&w[j0 + 4];
    bf16x8 pv = *(const bf16x8*)&Pdb[(long long)c * 1024 + j0];
    bf16x8 qv = *(const bf16x8*)&Qtb[(long long)c * 512 + j0];
    bf16x8 tv = *(const bf16x8*)&T[(long long)b * 262144 + (long long)c * 512 + j0];
    float sj[8] = {s0.x, s0.y, s0.z, s0.w, s1.x, s1.y, s1.z, s1.w};
    float wj[8] = {w0.x, w0.y, w0.z, w0.w, w1.x, w1.y, w1.z, w1.w};
    float aps = 0.f, asq = 0.f, atw = 0.f, asw = 0.f;
#pragma unroll
    for (int t = 0; t < 8; ++t) {
        aps = fmaf((float)pv[t], sj[t], aps);
        asq = fmaf((float)qv[t], sj[t], asq);
        atw = fmaf((float)tv[t], wj[t], atw);
        asw = fmaf(sj[t], wj[t], asw);
    }
#pragma unroll
    for (int m = 1; m < 64; m <<= 1) {
        aps += __shfl_xor(aps, m);
        asq += __shfl_xor(asq, m);
        atw += __shfl_xor(atw, m);
        asw += __shfl_xor(asw, m);
    }
    if (lane == 0) {
        ps[idx] = aps; sq[idx] = asq;
        float kp = *kap;
        a2[idx] = (atw + u[c] * asw + aps * kp) * (1.f / 3136.f) + u[c] * kp + bo[c];
    }
}

#define SWZ64(row) ((row) & 7)

// G GEMM (y<36) with symmetric mirroring + WEIGHT PRECOMPUTE (y in [36,45)).
// G: 64x64 tile, BK=64, operands = xnp; x = batch + 8*ks; y = tri pair index.
// Weight blocks: blk = (y-36)*16 + x in [0,130):
//   [0,64) Pd tile; [64,128) Qt tile; 128,129 u/r/w vectors.
// Complementary pipes: G = MFMA/LDS-heavy, weights = VALU/global-heavy.
__global__ __launch_bounds__(256)
void mfma_g_w(const __hip_bfloat16* __restrict__ A, long long sA, int lda,
              __hip_bfloat16* __restrict__ C, long long sC, int ldc, int kLen,
              const float* __restrict__ wo, const float* __restrict__ wv,
              const float* __restrict__ wq, const float* __restrict__ wk,
              const float* __restrict__ bq, const float* __restrict__ bk,
              const float* __restrict__ bv,
              __hip_bfloat16* __restrict__ Pdb, __hip_bfloat16* __restrict__ Qtb,
              float* __restrict__ u, float* __restrict__ r, float* __restrict__ w,
              float* __restrict__ kap)
{
    constexpr int BKT = 64;
    constexpr int CPR = BKT / 8;
    constexpr int NC = 64 * CPR / 256;
    constexpr int LSZ = 64 * BKT;
    __shared__ __align__(16) char arena[4 * LSZ * 2];   // 32KB: G dbuf / weight smem
    const int tid = threadIdx.x;

    if (blockIdx.y >= 36) {
        // ---------- weight path (R9 software-pipelined LDS GEMM) ----------
        const int blk = (blockIdx.y - 36) * 16 + blockIdx.x;
        if (blk >= 130) return;
        if (blk >= 128) {
            int c = (blk - 128) * 256 + tid;
            float su = 0.f, sr = 0.f, sw = 0.f;
            for (int e = 0; e < 256; ++e) {
                su = fmaf(wo[(long long)c * 256 + e], bv[e], su);
                sr = fmaf(bk[e], wq[(long long)e * 512 + c], sr);
                sw = fmaf(wk[(long long)e * 512 + c], bq[e], sw);
            }
            u[c] = su; r[c] = sr; w[c] = sw;
            if (c == 0) {
                float k2 = 0.f;
                for (int e = 0; e < 256; ++e) k2 = fmaf(bk[e], bq[e], k2);
                *kap = k2;
            }
            return;
        }
        const bool doQ = (blk >= 64);
        const int tt = blk & 63;
        const int m0 = (tt >> 3) * 64, n0 = (tt & 7) * 64;
        float* smem = (float*)arena;
        float (*As)[68] = (float(*)[68])smem;
        float (*Bs)[68] = (float(*)[68])(smem + 16 * 68);
        const int tx = tid & 15, ty = tid >> 4;
        const int lk = tid >> 4, lc = (tid & 15) * 4;
        const int lr = tid >> 2, lk4 = (tid & 3) * 4;
        float acc[4][4] = {};

        float4 av, bv4, nav, nbv;
        if (doQ) {
            av  = *(const float4*)&wq[(long long)lk * 512 + m0 + lc];
            bv4 = *(const float4*)&wk[(long long)lk * 512 + n0 + lc];
        } else {
            av  = *(const float4*)&wo[(long long)(m0 + lr) * 256 + lk4];
            bv4 = *(const float4*)&wv[(long long)lk * 512 + n0 + lc];
        }
        for (int k0 = 0; k0 < 256; k0 += 16) {
            __syncthreads();
            if (doQ) {
                *(float4*)&As[lk][lc] = av;
            } else {
                As[lk4 + 0][lr] = av.x; As[lk4 + 1][lr] = av.y;
                As[lk4 + 2][lr] = av.z; As[lk4 + 3][lr] = av.w;
            }
            *(float4*)&Bs[lk][lc] = bv4;
            __syncthreads();
            if (k0 + 16 < 256) {
                if (doQ) {
                    nav = *(const float4*)&wq[(long long)(k0 + 16 + lk) * 512 + m0 + lc];
                    nbv = *(const float4*)&wk[(long long)(k0 + 16 + lk) * 512 + n0 + lc];
                } else {
                    nav = *(const float4*)&wo[(long long)(m0 + lr) * 256 + k0 + 16 + lk4];
                    nbv = *(const float4*)&wv[(long long)(k0 + 16 + lk) * 512 + n0 + lc];
                }
            }
#pragma unroll
            for (int kk = 0; kk < 16; ++kk) {
                float a[4], b[4];
#pragma unroll
                for (int i = 0; i < 4; ++i) { a[i] = As[kk][ty * 4 + i]; b[i] = Bs[kk][tx * 4 + i]; }
#pragma unroll
                for (int i = 0; i < 4; ++i)
#pragma unroll
                    for (int j = 0; j < 4; ++j) acc[i][j] = fmaf(a[i], b[j], acc[i][j]);
            }
            av = nav; bv4 = nbv;
        }
        const int mo = m0 + ty * 4, no = n0 + tx * 4;
        if (doQ) {
#pragma unroll
            for (int i = 0; i < 4; ++i)
#pragma unroll
                for (int j = 0; j < 4; ++j)
                    Qtb[(long long)(mo + i) * 512 + no + j] = __float2bfloat16(acc[i][j]);
        } else {
#pragma unroll
            for (int i = 0; i < 4; ++i)
#pragma unroll
                for (int j = 0; j < 4; ++j) {
                    __hip_bfloat16 v = __float2bfloat16(acc[i][j]);
                    Pdb[(long long)(mo + i) * 1024 + no + j] = v;
                    Pdb[(long long)(mo + i) * 1024 + no + j + 512] = v;
                }
        }
        return;
    }

    // ---------- G path (counted-vmcnt dbuf K-loop, unchanged) ----------
    __hip_bfloat16* As = (__hip_bfloat16*)arena;            // 2*LSZ bf16
    __hip_bfloat16* Bs = As + 2 * LSZ;                      // 2*LSZ bf16
    const int lane = tid & 63;
    const int wv_ = tid >> 6;
    const int wm = (wv_ >> 1) << 5;
    const int wn = (wv_ & 1) << 5;
    const int ln = lane & 15;
    const int hi = lane >> 4;
    const int bx = blockIdx.x;
    const int batch = bx & 7, ks = bx >> 3;
    int p = blockIdx.y, mt = 0;
    while (p >= 8 - mt) { p -= 8 - mt; ++mt; }
    const int nt = mt + p;
    const int m0 = mt << 6, n0 = nt << 6;
    const long long k0 = (long long)ks * kLen;

    const __hip_bfloat16* gA[NC];
    const __hip_bfloat16* gB[NC];
#pragma unroll
    for (int q0 = 0; q0 < NC; ++q0) {
        int q = tid + 256 * q0;
        int row = q / CPR;
        int c = (q % CPR) ^ SWZ64(row);
        gA[q0] = A + batch * sA + (long long)(m0 + row) * lda + k0 + c * 8;
        gB[q0] = A + batch * sA + (long long)(n0 + row) * lda + k0 + c * 8;
    }
    floatx4 acc[2][2] = {};
    const int nK = kLen / BKT;

#pragma unroll
    for (int q0 = 0; q0 < NC; ++q0) {
        load_lds16(gA[q0], As + (tid + 256 * q0) * 8);
        load_lds16(gB[q0], Bs + (tid + 256 * q0) * 8);
        gA[q0] += BKT; gB[q0] += BKT;
    }

    int cur = 0;
    for (int kt = 0; kt < nK; ++kt) {
        if (kt + 1 < nK) {
            const int off = (cur ^ 1) * LSZ;
#pragma unroll
            for (int q0 = 0; q0 < NC; ++q0) {
                load_lds16(gA[q0], As + off + (tid + 256 * q0) * 8);
                load_lds16(gB[q0], Bs + off + (tid + 256 * q0) * 8);
                gA[q0] += BKT; gB[q0] += BKT;
            }
            asm volatile("s_waitcnt vmcnt(4)" ::: "memory");
        } else {
            asm volatile("s_waitcnt vmcnt(0)" ::: "memory");
        }
        __builtin_amdgcn_s_barrier();
        const __hip_bfloat16* Ac = As + cur * LSZ;
        const __hip_bfloat16* Bc = Bs + cur * LSZ;
#pragma unroll
        for (int kk = 0; kk < BKT / 32; ++kk) {
            const int cidx = kk * 4 + hi;
            bf16x8 af[2], bfr[2];
#pragma unroll
            for (int i = 0; i < 2; ++i) {
                int row = wm + i * 16 + ln;
                af[i] = *(const bf16x8*)(Ac + row * BKT + ((cidx ^ SWZ64(row)) << 3));
            }
#pragma unroll
            for (int j = 0; j < 2; ++j) {
                int row = wn + j * 16 + ln;
                bfr[j] = *(const bf16x8*)(Bc + row * BKT + ((cidx ^ SWZ64(row)) << 3));
            }
#pragma unroll
            for (int i = 0; i < 2; ++i)
#pragma unroll
                for (int j = 0; j < 2; ++j)
                    acc[i][j] = __builtin_amdgcn_mfma_f32_16x16x32_bf16(af[i], bfr[j], acc[i][j], 0, 0, 0);
        }
        if (kt + 1 < nK) {
            __builtin_amdgcn_s_barrier();
            cur ^= 1;
        }
    }

    // C/D layout: col = lane&15, row = (lane>>4)*4 + r  [m89-verified]
    __hip_bfloat16* Cb = C + batch * sC + ks * 512;
#pragma unroll
    for (int i = 0; i < 2; ++i) {
        int mb = m0 + wm + i * 16 + hi * 4;
#pragma unroll
        for (int j = 0; j < 2; ++j) {
            int nl = n0 + wn + j * 16 + ln;
            bh4 mv;
            mv.x = __float2bfloat16(acc[i][j][0]);
            mv.y = __float2bfloat16(acc[i][j][1]);
            mv.z = __float2bfloat16(acc[i][j][2]);
            mv.w = __float2bfloat16(acc[i][j][3]);
            Cb[(long long)(mb + 0) * ldc + nl] = mv.x;
            Cb[(long long)(mb + 1) * ldc + nl] = mv.y;
            Cb[(long long)(mb + 2) * ldc + nl] = mv.z;
            Cb[(long long)(mb + 3) * ldc + nl] = mv.w;
            if (mt != nt)
                *(bh4*)&Cb[(long long)nl * ldc + mb] = mv;   // mirrored tile
        }
    }
}

// Small MFMA GEMM, 64x64 tile, BK=64, operands K-contiguous.
// MODE 5: plain bf16 store.
// MODE 6: bf16 store of (acc + u[m]·sq[b][n] + ps[b][m]·r[n])/N + u[m]·r[n]
//         + IDENTITY on the diagonal (residual x folded into A2).
// Counted-vmcnt double-buffered K-loop.
template<int MODE>
__global__ __launch_bounds__(256)
void mfma_sm(const __hip_bfloat16* __restrict__ A, long long sA, int lda,
             const __hip_bfloat16* __restrict__ B, long long sB, int ldb,
             __hip_bfloat16* __restrict__ C, long long sC, int ldc,
             const float* __restrict__ pu, const float* __restrict__ pr,
             const float* __restrict__ pps, const float* __restrict__ psq,
             int kLen)
{
    constexpr int BKT = 64;
    constexpr int CPR = BKT / 8;
    constexpr int NC = 64 * CPR / 256;
    constexpr int LSZ = 64 * BKT;
    __shared__ __hip_bfloat16 As[2 * LSZ];
    __shared__ __hip_bfloat16 Bs[2 * LSZ];
    const int tid = threadIdx.x;
    const int lane = tid & 63;
    const int w = tid >> 6;
    const int wm = (w >> 1) << 5;
    const int wn = (w & 1) << 5;
    const int ln = lane & 15;
    const int hi = lane >> 4;
    const int batch = blockIdx.x;
    const int m0 = blockIdx.z << 6;
    const int n0 = blockIdx.y << 6;

    const __hip_bfloat16* gA[NC];
    const __hip_bfloat16* gB[NC];
#pragma unroll
    for (int q0 = 0; q0 < NC; ++q0) {
        int q = tid + 256 * q0;
        int row = q / CPR;
        int c = (q % CPR) ^ SWZ64(row);
        gA[q0] = A + batch * sA + (long long)(m0 + row) * lda + c * 8;
        gB[q0] = B + batch * sB + (long long)(n0 + row) * ldb + c * 8;
    }
    floatx4 acc[2][2] = {};
    const int nK = kLen / BKT;

#pragma unroll
    for (int q0 = 0; q0 < NC; ++q0) {
        load_lds16(gA[q0], As + (tid + 256 * q0) * 8);
        load_lds16(gB[q0], Bs + (tid + 256 * q0) * 8);
        gA[q0] += BKT; gB[q0] += BKT;
    }

    int cur = 0;
    for (int kt = 0; kt < nK; ++kt) {
        if (kt + 1 < nK) {
            const int off = (cur ^ 1) * LSZ;
#pragma unroll
            for (int q0 = 0; q0 < NC; ++q0) {
                load_lds16(gA[q0], As + off + (tid + 256 * q0) * 8);
                load_lds16(gB[q0], Bs + off + (tid + 256 * q0) * 8);
                gA[q0] += BKT; gB[q0] += BKT;
            }
            asm volatile("s_waitcnt vmcnt(4)" ::: "memory");
        } else {
            asm volatile("s_waitcnt vmcnt(0)" ::: "memory");
        }
        __builtin_amdgcn_s_barrier();
        const __hip_bfloat16* Ac = As + cur * LSZ;
        const __hip_bfloat16* Bc = Bs + cur * LSZ;
#pragma unroll
        for (int kk = 0; kk < BKT / 32; ++kk) {
            const int cidx = kk * 4 + hi;
            bf16x8 af[2], bfr[2];
#pragma unroll
            for (int i = 0; i < 2; ++i) {
                int row = wm + i * 16 + ln;
                af[i] = *(const bf16x8*)(Ac + row * BKT + ((cidx ^ SWZ64(row)) << 3));
            }
#pragma unroll
            for (int j = 0; j < 2; ++j) {
                int row = wn + j * 16 + ln;
                bfr[j] = *(const bf16x8*)(Bc + row * BKT + ((cidx ^ SWZ64(row)) << 3));
            }
#pragma unroll
            for (int i = 0; i < 2; ++i)
#pragma unroll
                for (int j = 0; j < 2; ++j)
                    acc[i][j] = __builtin_amdgcn_mfma_f32_16x16x32_bf16(af[i], bfr[j], acc[i][j], 0, 0, 0);
        }
        if (kt + 1 < nK) {
            __builtin_amdgcn_s_barrier();
            cur ^= 1;
        }
    }

    __hip_bfloat16* Cb = C + batch * sC;
#pragma unroll
    for (int i = 0; i < 2; ++i) {
        int mb = m0 + wm + i * 16 + hi * 4;
#pragma unroll
        for (int r = 0; r < 4; ++r) {
#pragma unroll
            for (int j = 0; j < 2; ++j) {
                int nl = n0 + wn + j * 16 + ln;
                float v = acc[i][j][r];
                if (MODE == 6) {
                    float uu = pu[mb + r], rr = pr[nl];
                    v = (v + uu * psq[batch * 512 + nl] + pps[batch * 512 + mb + r] * rr)
                        * (1.f / 3136.f) + uu * rr;
                    if (mb + r == nl) v += 1.f;   // residual fold: A2 += I
                }
                Cb[(long long)(mb + r) * ldc + nl] = __float2bfloat16(v);
            }
        }
    }
}

// B-side swizzle for the transpose-scatter LDS tile: granule ^= SWZ_B(n).
#define SWZB(nr) (((nr) & 7) ^ (((nr) >> 3) & 7))

// Final MFMA GEMM: 64(M)x128(N) tile, 4 waves (64x32 each), BK=64.
// A (A2b) staged via global_load_lds. B staged FROM xnp [c][n] via reg-load +
// ds_write_b16 transpose-scatter with SWZB granule swizzle (R7-verified, 43us).
__global__ __launch_bounds__(256)
void mfma64(const __hip_bfloat16* __restrict__ A, long long sA, int lda,
            const __hip_bfloat16* __restrict__ Bn, long long sB, int ldb,
            float* __restrict__ C, long long sC, int ldc,
            const float* __restrict__ bias, int sBias,
            int kLen, int Nreal)
{
    constexpr int BKT = 64;
    constexpr int CPR = BKT / 8;
    constexpr int NA = 64 * CPR / 256;      // 2 A-loads/thread
    __shared__ __hip_bfloat16 As[64 * BKT];              // 8 KB
    __shared__ __align__(16) short Bs[128 * 64];         // 16 KB, [n][c] swizzled
    const int tid = threadIdx.x;
    const int lane = tid & 63;
    const int w = tid >> 6;
    const int ln = lane & 15;
    const int hi = lane >> 4;
    const int batch = blockIdx.x;
    const int m0 = blockIdx.z << 6;
    const int n0 = blockIdx.y << 7;

    const __hip_bfloat16* gA[NA];
#pragma unroll
    for (int q0 = 0; q0 < NA; ++q0) {
        int q = tid + 256 * q0;
        int row = q / CPR;
        int c = (q % CPR) ^ SWZ64(row);
        gA[q0] = A + batch * sA + (long long)(m0 + row) * lda + c * 8;
    }
    // B staging map: bc = c within K-tile (16 rows/wave), bq = n-chunk phase.
    const int bc = tid >> 2;      // 0..63
    const int bq = tid & 3;       // 0..3
    const short* bbase = (const short*)(Bn + batch * sB)
                         + (long long)bc * ldb + n0 + bq * 8;
    const int g = bc >> 3;

    floatx4 acc[4][2] = {};
    const int nK = kLen / BKT;
    for (int kt = 0; kt < nK; ++kt) {
        // B register loads (4 x 16B; lanes 4-per-row -> full 64B lines)
        s16x8 vb[4];
        const short* bp = bbase + (long long)kt * 64 * ldb;
#pragma unroll
        for (int m = 0; m < 4; ++m)
            vb[m] = *(const s16x8*)(bp + m * 32);
        // A async staging
#pragma unroll
        for (int q0 = 0; q0 < NA; ++q0) {
            load_lds16(gA[q0], As + (tid + 256 * q0) * 8);
            gA[q0] += BKT;
        }
        // transpose-scatter B into LDS (compiler inserts the vmcnt for vb)
#pragma unroll
        for (int m = 0; m < 4; ++m) {
            const int nb = (bq + 4 * m) * 8;
#pragma unroll
            for (int k = 0; k < 8; ++k) {
                const int nr = nb + k;
                Bs[nr * 64 + (((g ^ SWZB(nr)) & 7) << 3) + (bc & 7)] = vb[m][k];
            }
        }
        __syncthreads();   // drains A (vmcnt) + B scatter (lgkm)
#pragma unroll
        for (int kk = 0; kk < BKT / 32; ++kk) {
            const int cidx = kk * 4 + hi;
            bf16x8 af[4], bfr[2];
#pragma unroll
            for (int i = 0; i < 4; ++i) {
                int row = i * 16 + ln;
                af[i] = *(const bf16x8*)(As + row * BKT + ((cidx ^ SWZ64(row)) << 3));
            }
#pragma unroll
            for (int j = 0; j < 2; ++j) {
                int row = w * 32 + j * 16 + ln;
                bfr[j] = *(const bf16x8*)((const __hip_bfloat16*)Bs
                          + row * 64 + (((cidx ^ SWZB(row)) & 7) << 3));
            }
#pragma unroll
            for (int i = 0; i < 4; ++i)
#pragma unroll
                for (int j = 0; j < 2; ++j)
                    acc[i][j] = __builtin_amdgcn_mfma_f32_16x16x32_bf16(af[i], bfr[j], acc[i][j], 0, 0, 0);
        }
        __syncthreads();   // LDS fully read -> safe to restage
    }

    float* Cb = C + batch * sC;
#pragma unroll
    for (int i = 0; i < 4; ++i) {
        int mb = m0 + i * 16 + hi * 4;
#pragma unroll
        for (int r = 0; r < 4; ++r) {
            float bb = bias[batch * sBias + mb + r];
#pragma unroll
            for (int j = 0; j < 2; ++j) {
                int nl = n0 + w * 32 + j * 16 + ln;
                if (nl < Nreal) {
                    Cb[(long long)(mb + r) * ldc + nl] = acc[i][j][r] + bb;
                }
            }
        }
    }
}

extern "C" void kernel_launch(void* const* d_in, const int* in_sizes, int n_in,
                              void* d_out, int out_size, void* d_ws, size_t ws_size,
                              hipStream_t stream)
{
    const float* x  = (const float*)d_in[0];
    const float* wq = (const float*)d_in[1];
    const float* bq = (const float*)d_in[2];
    const float* wk = (const float*)d_in[3];
    const float* bk = (const float*)d_in[4];
    const float* wv = (const float*)d_in[5];
    const float* bv = (const float*)d_in[6];
    const float* wo = (const float*)d_in[7];
    const float* bo = (const float*)d_in[8];
    float* out = (float*)d_out;

    const int N = 3136;
    const long long xs = 512LL * N;               // 1,605,632
    const long long xs2 = 512LL * 3200;           // xnp per-batch stride

    // d_out scratch (dead before the final GEMM overwrites it with out):
    char* ob = (char*)d_out;
    __hip_bfloat16* Gp2 = (__hip_bfloat16*)(ob + 26214400);    // 8x512x1024 bf16 = 8,388,608
    __hip_bfloat16* Tb  = (__hip_bfloat16*)(ob + 34603008);    // 8x512x512 bf16 = 4,194,304

    // ws (~32.05 MB). xnp lives HERE (mfma64 reads it while writing d_out).
    char* wsb = (char*)d_ws;
    __hip_bfloat16* xnp = (__hip_bfloat16*)wsb;                // 26,214,400
    __hip_bfloat16* A2b = (__hip_bfloat16*)(wsb + 26214400);   //  4,194,304
    __hip_bfloat16* Pdb = (__hip_bfloat16*)(wsb + 30408704);   //  1,048,576
    __hip_bfloat16* Qtb = (__hip_bfloat16*)(wsb + 31457280);   //    524,288
    float* sv  = (float*)(wsb + 31981568);                     //     16,384
    float* u_  = (float*)(wsb + 31997952);                     //      2,048
    float* r_  = (float*)(wsb + 32000000);                     //      2,048
    float* w_  = (float*)(wsb + 32002048);                     //      2,048
    float* kap = (float*)(wsb + 32004096);                     //         16
    float* ps  = (float*)(wsb + 32004112);                     //     16,384
    float* sq  = (float*)(wsb + 32020496);                     //     16,384
    float* a2v = (float*)(wsb + 32036880);                     //     16,384

    // 0) zero the rowsum accumulator (stream-ordered)
    hipMemsetAsync(sv, 0, 512 * 8 * sizeof(float), stream);

    // 1) pure streaming x->xnp + rowsums (now directly measurable)
    conv_x<<<dim3(50, 8, 8), 256, 0, stream>>>(x, xnp, sv);

    // 2) Gp2 = partials of X·X^T (y<36) + weight precompute (y in [36,45))
    //    — weight path hidden under G's MFMA envelope
    mfma_g_w<<<dim3(16, 45), 256, 0, stream>>>(
        xnp, xs2, 3200, Gp2, 524288, 1024, 1600,
        wo, wv, wq, wk, bq, bk, bv, Pdb, Qtb, u_, r_, w_, kap);

    // 3) T = Pd·Gp2  (K=1024 folds the split-K reduce)
    mfma_sm<5><<<dim3(8, 8, 8), 256, 0, stream>>>(
        Pdb, 0, 1024, Gp2, 524288, 1024, Tb, 262144, 512,
        nullptr, nullptr, nullptr, nullptr, 1024);

    // 4) ps = P·s, sq = Qt·s, a2 = [T·w + u(s·w) + ps·κ]/N + uκ + bo
    vec2_kernel<<<1024, 256, 0, stream>>>(Tb, Pdb, Qtb, sv, u_, w_, kap, bo, ps, sq, a2v);

    // 5) A2 = [T·Q + u·sq^T + ps·r^T]/N + u·r^T + I  -> bf16
    mfma_sm<6><<<dim3(8, 8, 8), 256, 0, stream>>>(
        Tb, 262144, 512, Qtb, 0, 512, A2b, 262144, 512,
        u_, r_, ps, sq, 512);

    // 6) out = (A2+I)·X + a2   (M=512, N=3136, K=512), B from xnp via
    //    transpose-scatter staging
    mfma64<<<dim3(8, 25, 8), 256, 0, stream>>>(
        A2b, 262144, 512, xnp, xs2, 3200,
        out, xs, N, a2v, 512, 512, N);
}